// Round 3
// baseline (897.782 us; speedup 1.0000x reference)
//
#include <hip/hip_runtime.h>
#include <hip/hip_bf16.h>

#define L_SEQ 2048
#define BATCH 2
#define EMB   1024
#define NH    16
#define HDIM  64
#define BHEAD 32
#define MROWS 4096

typedef short bf16x8 __attribute__((ext_vector_type(8)));
typedef float f32x4  __attribute__((ext_vector_type(4)));
typedef unsigned short u16;

static __device__ __forceinline__ u16 f2bf(float x) {
    unsigned int u = __float_as_uint(x);
    unsigned int r = (u + 0x7fffu + ((u >> 16) & 1u)) >> 16;
    return (u16)r;
}

// ---------------- cast f32 -> bf16 (vectorized 4/thread) ----------------
__global__ void cast_f32_bf16(const float* __restrict__ src, u16* __restrict__ dst, int n4) {
    int i = blockIdx.x * blockDim.x + threadIdx.x;
    if (i >= n4) return;
    float4 v = reinterpret_cast<const float4*>(src)[i];
    ushort4 o;
    o.x = f2bf(v.x); o.y = f2bf(v.y); o.z = f2bf(v.z); o.w = f2bf(v.w);
    reinterpret_cast<ushort4*>(dst)[i] = o;
}

// ---------------- fused QKV GEMM: C = A * W^T, scatter to [BH][L][64] ----------------
// A: [4096][1024] bf16 (query rows l*B+b), W row-major [N][K] == B^T input.
__global__ __launch_bounds__(256) void gemm_qkv(
    const u16* __restrict__ A,
    const u16* __restrict__ Wq, const u16* __restrict__ Wk, const u16* __restrict__ Wv,
    const float* __restrict__ bq, const float* __restrict__ bv,
    u16* __restrict__ qo, u16* __restrict__ ko, u16* __restrict__ vo)
{
    __shared__ u16 As[128][72];
    __shared__ u16 Bs[128][72];
    const int tid = threadIdx.x;
    const int l = tid & 63, w = tid >> 6;
    const int lg = l >> 4, lr = l & 15;
    const int wr = w >> 1, wc = w & 1;
    const int bm = blockIdx.y, bn = blockIdx.x, z = blockIdx.z;
    const u16* __restrict__ W = (z == 0) ? Wq : (z == 1) ? Wk : Wv;

    f32x4 acc[4][4] = {};

    for (int kb = 0; kb < 16; ++kb) {
        #pragma unroll
        for (int i = 0; i < 4; ++i) {
            int c = tid + i * 256;            // 0..1023 chunks of 8
            int row = c >> 3, col = (c & 7) * 8;
            *reinterpret_cast<bf16x8*>(&As[row][col]) =
                *reinterpret_cast<const bf16x8*>(&A[(size_t)(bm * 128 + row) * 1024 + kb * 64 + col]);
            *reinterpret_cast<bf16x8*>(&Bs[row][col]) =
                *reinterpret_cast<const bf16x8*>(&W[(size_t)(bn * 128 + row) * 1024 + kb * 64 + col]);
        }
        __syncthreads();
        #pragma unroll
        for (int s = 0; s < 2; ++s) {
            bf16x8 af[4], bfr[4];
            #pragma unroll
            for (int mt = 0; mt < 4; ++mt)
                af[mt] = *reinterpret_cast<const bf16x8*>(&As[wr * 64 + mt * 16 + lr][s * 32 + lg * 8]);
            #pragma unroll
            for (int nt = 0; nt < 4; ++nt)
                bfr[nt] = *reinterpret_cast<const bf16x8*>(&Bs[wc * 64 + nt * 16 + lr][s * 32 + lg * 8]);
            #pragma unroll
            for (int mt = 0; mt < 4; ++mt)
                #pragma unroll
                for (int nt = 0; nt < 4; ++nt)
                    acc[mt][nt] = __builtin_amdgcn_mfma_f32_16x16x32_bf16(af[mt], bfr[nt], acc[mt][nt], 0, 0, 0);
        }
        __syncthreads();
    }

    const float* __restrict__ bias = (z == 0) ? bq : (z == 2) ? bv : nullptr;
    const float scale = (z == 0) ? 0.125f : 1.0f;
    u16* __restrict__ outp = (z == 0) ? qo : (z == 1) ? ko : vo;
    #pragma unroll
    for (int mt = 0; mt < 4; ++mt)
        #pragma unroll
        for (int nt = 0; nt < 4; ++nt)
            #pragma unroll
            for (int r = 0; r < 4; ++r) {
                int m = bm * 128 + wr * 64 + mt * 16 + lg * 4 + r;
                int n = bn * 128 + wc * 64 + nt * 16 + lr;
                float v = acc[mt][nt][r];
                if (bias) v += bias[n];
                v *= scale;
                int li = m >> 1, b = m & 1, h = n >> 6, d = n & 63;
                outp[(size_t)((b * NH + h) * L_SEQ + li) * HDIM + d] = f2bf(v);
            }
}

// ---------------- fused attention: scores+bias, online softmax, PV ----------------
// grid (qblk=32, head=32), 256 threads = 4 waves, wave owns 16 q-rows.
__global__ __launch_bounds__(256) void attn_kernel(
    const u16* __restrict__ qb, const u16* __restrict__ kbuf, const u16* __restrict__ vbuf,
    const float* __restrict__ bias, float* __restrict__ attn_out)
{
    __shared__ u16 Vt[64][72];          // V^T tile: [d][k]
    __shared__ u16 Plds[4][16][72];     // per-wave P tile
    const int head = blockIdx.y, qblk = blockIdx.x;
    const int tid = threadIdx.x, w = tid >> 6, l = tid & 63;
    const int lg = l >> 4, lr = l & 15;
    const size_t hbase = (size_t)head * L_SEQ * HDIM;

    // Q fragments (A-operand): row = lr, k = s*32 + lg*8 + j
    bf16x8 aq[2];
    {
        const u16* qp = qb + hbase + (size_t)(qblk * 64 + w * 16 + lr) * HDIM;
        aq[0] = *reinterpret_cast<const bf16x8*>(qp + lg * 8);
        aq[1] = *reinterpret_cast<const bf16x8*>(qp + 32 + lg * 8);
    }

    float mrun[4], lrun[4];
    f32x4 accO[4] = {};
    #pragma unroll
    for (int r = 0; r < 4; ++r) { mrun[r] = -INFINITY; lrun[r] = 0.f; }

    for (int kb = 0; kb < 32; ++kb) {
        // prefetch bias for this tile into regs (overlaps with staging + MFMA)
        float bl[4][4];
        {
            const size_t bbase = ((size_t)head * L_SEQ + qblk * 64 + w * 16) * L_SEQ + kb * 64;
            #pragma unroll
            for (int nt = 0; nt < 4; ++nt)
                #pragma unroll
                for (int r = 0; r < 4; ++r)
                    bl[nt][r] = bias[bbase + (size_t)(lg * 4 + r) * L_SEQ + nt * 16 + lr];
        }
        // stage V transposed: thread reads v[krow][dc*8..+8], writes Vt[d][krow]
        #pragma unroll
        for (int i = 0; i < 2; ++i) {
            int c = tid + i * 256;
            int krow = c & 63, dc = c >> 6;
            bf16x8 vv = *reinterpret_cast<const bf16x8*>(
                &vbuf[hbase + (size_t)(kb * 64 + krow) * HDIM + dc * 8]);
            #pragma unroll
            for (int j = 0; j < 8; ++j) Vt[dc * 8 + j][krow] = (u16)vv[j];
        }
        __syncthreads();

        // S = Q K^T  (K frags direct from global; L2-resident)
        f32x4 accS[4] = {};
        #pragma unroll
        for (int s = 0; s < 2; ++s)
            #pragma unroll
            for (int nt = 0; nt < 4; ++nt) {
                bf16x8 bfr = *reinterpret_cast<const bf16x8*>(
                    &kbuf[hbase + (size_t)(kb * 64 + nt * 16 + lr) * HDIM + s * 32 + lg * 8]);
                accS[nt] = __builtin_amdgcn_mfma_f32_16x16x32_bf16(aq[s], bfr, accS[nt], 0, 0, 0);
            }
        #pragma unroll
        for (int nt = 0; nt < 4; ++nt)
            #pragma unroll
            for (int r = 0; r < 4; ++r)
                accS[nt][r] += bl[nt][r];

        // online softmax: row = lg*4 + r, reduce across 16 lanes (cols)
        float mnew[4], sc[4];
        #pragma unroll
        for (int r = 0; r < 4; ++r) {
            float t = fmaxf(fmaxf(accS[0][r], accS[1][r]), fmaxf(accS[2][r], accS[3][r]));
            t = fmaxf(t, __shfl_xor(t, 1, 64));
            t = fmaxf(t, __shfl_xor(t, 2, 64));
            t = fmaxf(t, __shfl_xor(t, 4, 64));
            t = fmaxf(t, __shfl_xor(t, 8, 64));
            mnew[r] = fmaxf(mrun[r], t);
            sc[r] = __expf(mrun[r] - mnew[r]);
            mrun[r] = mnew[r];
        }
        float rsum[4] = {0.f, 0.f, 0.f, 0.f};
        #pragma unroll
        for (int nt = 0; nt < 4; ++nt)
            #pragma unroll
            for (int r = 0; r < 4; ++r) {
                float p = __expf(accS[nt][r] - mnew[r]);
                accS[nt][r] = p;
                rsum[r] += p;
            }
        #pragma unroll
        for (int r = 0; r < 4; ++r) {
            float t = rsum[r];
            t += __shfl_xor(t, 1, 64);
            t += __shfl_xor(t, 2, 64);
            t += __shfl_xor(t, 4, 64);
            t += __shfl_xor(t, 8, 64);
            lrun[r] = lrun[r] * sc[r] + t;
            #pragma unroll
            for (int nt = 0; nt < 4; ++nt) accO[nt][r] *= sc[r];
        }
        // P -> LDS (bf16) for A-operand relayout
        #pragma unroll
        for (int nt = 0; nt < 4; ++nt)
            #pragma unroll
            for (int r = 0; r < 4; ++r)
                Plds[w][lg * 4 + r][nt * 16 + lr] = f2bf(accS[nt][r]);
        __syncthreads();

        // O += P V : A = P (16x64), B = Vt
        #pragma unroll
        for (int s = 0; s < 2; ++s) {
            bf16x8 pf = *reinterpret_cast<const bf16x8*>(&Plds[w][lr][s * 32 + lg * 8]);
            #pragma unroll
            for (int nd = 0; nd < 4; ++nd) {
                bf16x8 vf = *reinterpret_cast<const bf16x8*>(&Vt[nd * 16 + lr][s * 32 + lg * 8]);
                accO[nd] = __builtin_amdgcn_mfma_f32_16x16x32_bf16(pf, vf, accO[nd], 0, 0, 0);
            }
        }
        __syncthreads();   // protect Vt before next stage
    }

    // epilogue: write [L, B, E] f32
    const int b = head >> 4, h = head & 15;
    #pragma unroll
    for (int nd = 0; nd < 4; ++nd)
        #pragma unroll
        for (int r = 0; r < 4; ++r) {
            int qrow = qblk * 64 + w * 16 + lg * 4 + r;
            float o = accO[nd][r] / lrun[r];
            attn_out[(size_t)(qrow * BATCH + b) * EMB + h * HDIM + nd * 16 + lr] = o;
        }
}

// ---------------- LayerNorm over E, output bf16 ----------------
__global__ __launch_bounds__(256) void ln_kernel(
    const float* __restrict__ x, const float* __restrict__ g, const float* __restrict__ bb,
    u16* __restrict__ outp)
{
    const int row = blockIdx.x;
    const int tid = threadIdx.x;
    float4 v = reinterpret_cast<const float4*>(x + (size_t)row * EMB)[tid];
    float s = v.x + v.y + v.z + v.w;
    float sq = v.x * v.x + v.y * v.y + v.z * v.z + v.w * v.w;
    #pragma unroll
    for (int m = 1; m < 64; m <<= 1) {
        s  += __shfl_xor(s, m, 64);
        sq += __shfl_xor(sq, m, 64);
    }
    __shared__ float ps[4], pq[4];
    int w = tid >> 6;
    if ((tid & 63) == 0) { ps[w] = s; pq[w] = sq; }
    __syncthreads();
    s  = ps[0] + ps[1] + ps[2] + ps[3];
    sq = pq[0] + pq[1] + pq[2] + pq[3];
    float mu = s * (1.0f / EMB);
    float var = sq * (1.0f / EMB) - mu * mu;
    float rs = rsqrtf(var + 1e-5f);
    float4 gv = reinterpret_cast<const float4*>(g)[tid];
    float4 bv = reinterpret_cast<const float4*>(bb)[tid];
    ushort4 o;
    o.x = f2bf((v.x - mu) * rs * gv.x + bv.x);
    o.y = f2bf((v.y - mu) * rs * gv.y + bv.y);
    o.z = f2bf((v.z - mu) * rs * gv.z + bv.z);
    o.w = f2bf((v.w - mu) * rs * gv.w + bv.w);
    reinterpret_cast<ushort4*>(outp + (size_t)row * EMB)[tid] = o;
}

// ---------------- output projection GEMM, f32 epilogue ----------------
__global__ __launch_bounds__(256) void gemm_out(
    const u16* __restrict__ A, const u16* __restrict__ W,
    const float* __restrict__ bo, float* __restrict__ outp)
{
    __shared__ u16 As[128][72];
    __shared__ u16 Bs[128][72];
    const int tid = threadIdx.x;
    const int l = tid & 63, w = tid >> 6;
    const int lg = l >> 4, lr = l & 15;
    const int wr = w >> 1, wc = w & 1;
    const int bm = blockIdx.y, bn = blockIdx.x;

    f32x4 acc[4][4] = {};

    for (int kb = 0; kb < 16; ++kb) {
        #pragma unroll
        for (int i = 0; i < 4; ++i) {
            int c = tid + i * 256;
            int row = c >> 3, col = (c & 7) * 8;
            *reinterpret_cast<bf16x8*>(&As[row][col]) =
                *reinterpret_cast<const bf16x8*>(&A[(size_t)(bm * 128 + row) * 1024 + kb * 64 + col]);
            *reinterpret_cast<bf16x8*>(&Bs[row][col]) =
                *reinterpret_cast<const bf16x8*>(&W[(size_t)(bn * 128 + row) * 1024 + kb * 64 + col]);
        }
        __syncthreads();
        #pragma unroll
        for (int s = 0; s < 2; ++s) {
            bf16x8 af[4], bfr[4];
            #pragma unroll
            for (int mt = 0; mt < 4; ++mt)
                af[mt] = *reinterpret_cast<const bf16x8*>(&As[wr * 64 + mt * 16 + lr][s * 32 + lg * 8]);
            #pragma unroll
            for (int nt = 0; nt < 4; ++nt)
                bfr[nt] = *reinterpret_cast<const bf16x8*>(&Bs[wc * 64 + nt * 16 + lr][s * 32 + lg * 8]);
            #pragma unroll
            for (int mt = 0; mt < 4; ++mt)
                #pragma unroll
                for (int nt = 0; nt < 4; ++nt)
                    acc[mt][nt] = __builtin_amdgcn_mfma_f32_16x16x32_bf16(af[mt], bfr[nt], acc[mt][nt], 0, 0, 0);
        }
        __syncthreads();
    }
    #pragma unroll
    for (int mt = 0; mt < 4; ++mt)
        #pragma unroll
        for (int nt = 0; nt < 4; ++nt)
            #pragma unroll
            for (int r = 0; r < 4; ++r) {
                int m = bm * 128 + wr * 64 + mt * 16 + lg * 4 + r;
                int n = bn * 128 + wc * 64 + nt * 16 + lr;
                outp[(size_t)m * EMB + n] = acc[mt][nt][r] + bo[n];
            }
}

extern "C" void kernel_launch(void* const* d_in, const int* in_sizes, int n_in,
                              void* d_out, int out_size, void* d_ws, size_t ws_size,
                              hipStream_t stream)
{
    const float* query = (const float*)d_in[0];
    const float* attn_bias = (const float*)d_in[1];
    const float* Wq = (const float*)d_in[2];
    const float* bq = (const float*)d_in[3];
    const float* Wk = (const float*)d_in[4];
    const float* Wv = (const float*)d_in[5];
    const float* bv = (const float*)d_in[6];
    const float* Wo = (const float*)d_in[7];
    const float* bo = (const float*)d_in[8];
    const float* ln_g = (const float*)d_in[9];
    const float* ln_b = (const float*)d_in[10];
    float* out = (float*)d_out;

    char* ws = (char*)d_ws;
    u16* q_bf  = (u16*)(ws + (size_t)0);
    u16* k_bf  = (u16*)(ws + ((size_t)8  << 20));
    u16* v_bf  = (u16*)(ws + ((size_t)16 << 20));
    u16* x_bf  = (u16*)(ws + ((size_t)24 << 20));
    u16* wq_bf = (u16*)(ws + ((size_t)32 << 20));
    u16* wk_bf = (u16*)(ws + ((size_t)34 << 20));
    u16* wv_bf = (u16*)(ws + ((size_t)36 << 20));
    u16* wo_bf = (u16*)(ws + ((size_t)38 << 20));
    float* attn_f = (float*)(ws + ((size_t)40 << 20));
    u16* ln_bf = (u16*)(ws + ((size_t)56 << 20));

    // casts
    cast_f32_bf16<<<4096, 256, 0, stream>>>(query, x_bf, MROWS * EMB / 4);
    cast_f32_bf16<<<1024, 256, 0, stream>>>(Wq, wq_bf, EMB * EMB / 4);
    cast_f32_bf16<<<1024, 256, 0, stream>>>(Wk, wk_bf, EMB * EMB / 4);
    cast_f32_bf16<<<1024, 256, 0, stream>>>(Wv, wv_bf, EMB * EMB / 4);
    cast_f32_bf16<<<1024, 256, 0, stream>>>(Wo, wo_bf, EMB * EMB / 4);

    // QKV projections (z = 0:q, 1:k, 2:v)
    gemm_qkv<<<dim3(8, 32, 3), 256, 0, stream>>>(x_bf, wq_bf, wk_bf, wv_bf, bq, bv,
                                                 q_bf, k_bf, v_bf);
    // attention
    attn_kernel<<<dim3(32, 32), 256, 0, stream>>>(q_bf, k_bf, v_bf, attn_bias, attn_f);
    // layernorm
    ln_kernel<<<4096, 256, 0, stream>>>(attn_f, ln_g, ln_b, ln_bf);
    // output projection
    gemm_out<<<dim3(8, 32), 256, 0, stream>>>(ln_bf, wo_bf, bo, out);
}